// Round 1
// baseline (1319.040 us; speedup 1.0000x reference)
//
#include <hip/hip_runtime.h>

#define DIM 128

// ---------------------------------------------------------------------------
// Edge scatter: one 64-lane wave per edge, each lane owns 2 feature elements.
//   S[dst]   += w * x[src]       (for S @ W_j term)
//   A[dst]   += w * edge_attr[e] (for A @ W_e term)
//   deg[dst] += w                (for deg * (x @ W_i) term)
// ---------------------------------------------------------------------------
__global__ __launch_bounds__(256) void edge_scatter(
    const float* __restrict__ x,
    const int*   __restrict__ src,
    const int*   __restrict__ dst,
    const float* __restrict__ w,
    const float* __restrict__ eattr,
    float* __restrict__ S,
    float* __restrict__ A,
    float* __restrict__ deg,
    int E)
{
    int gid  = blockIdx.x * blockDim.x + threadIdx.x;
    int e    = gid >> 6;
    int lane = threadIdx.x & 63;
    if (e >= E) return;

    int   s  = src[e];
    int   d  = dst[e];
    float we = w[e];

    float2 xv = *(const float2*)(x     + (size_t)s * DIM + lane * 2);
    float2 ev = *(const float2*)(eattr + (size_t)e * DIM + lane * 2);

    float* Sd = S + (size_t)d * DIM + lane * 2;
    float* Ad = A + (size_t)d * DIM + lane * 2;

    atomicAdd(Sd,     we * xv.x);
    atomicAdd(Sd + 1, we * xv.y);
    atomicAdd(Ad,     we * ev.x);
    atomicAdd(Ad + 1, we * ev.y);
    if (lane == 0) atomicAdd(deg + d, we);
}

// ---------------------------------------------------------------------------
// Fused epilogue: out[n] = deg[n]*(x@W_i)[n] + (x@W_self)[n] + (S@W_j)[n] + (A@W_e)[n]
// Block: 256 threads -> 32 nodes x 128 cols, 4x4 register tile per thread.
// ---------------------------------------------------------------------------
__global__ __launch_bounds__(256) void fused_out(
    const float* __restrict__ x,
    const float* __restrict__ S,
    const float* __restrict__ A,
    const float* __restrict__ deg,
    const float* __restrict__ Wmsg,   // [384][128]: rows 0-127 Wi, 128-255 Wj, 256-383 We
    const float* __restrict__ Wself,  // [128][128]
    float* __restrict__ out,
    int N)
{
    __shared__ float xs[32][DIM];
    __shared__ float ss[32][DIM];
    __shared__ float as[32][DIM];
    __shared__ float dg[32];

    int t  = threadIdx.x;
    int n0 = blockIdx.x * 32;

    // Stage 32 rows of x, S, A into LDS (float4, fully coalesced).
    #pragma unroll
    for (int i = 0; i < 4; ++i) {
        int l  = i * 256 + t;       // 0..1023 float4 slots
        int n  = l >> 5;            // 0..31
        int k4 = (l & 31) << 2;     // 0..124
        if (n0 + n < N) {
            *(float4*)&xs[n][k4] = *(const float4*)(x + (size_t)(n0 + n) * DIM + k4);
            *(float4*)&ss[n][k4] = *(const float4*)(S + (size_t)(n0 + n) * DIM + k4);
            *(float4*)&as[n][k4] = *(const float4*)(A + (size_t)(n0 + n) * DIM + k4);
        } else {
            float4 z = {0.f, 0.f, 0.f, 0.f};
            *(float4*)&xs[n][k4] = z;
            *(float4*)&ss[n][k4] = z;
            *(float4*)&as[n][k4] = z;
        }
    }
    if (t < 32) dg[t] = (n0 + t < N) ? deg[n0 + t] : 0.f;
    __syncthreads();

    int tx = t & 31;        // column group: j0 = 4*tx
    int ty = t >> 5;        // node group:   r0 = 4*ty
    int j0 = tx * 4;
    int r0 = ty * 4;

    float acc_hi[4][4] = {{0.f}};   // x @ W_i  (scaled by deg at the end)
    float acc_m [4][4] = {{0.f}};   // x@Wself + S@Wj + A@We

    const float* Wi = Wmsg;
    const float* Wj = Wmsg + 128 * DIM;
    const float* We = Wmsg + 256 * DIM;

    for (int k4 = 0; k4 < DIM; k4 += 4) {
        float xv[4][4], sv[4][4], av[4][4];
        #pragma unroll
        for (int r = 0; r < 4; ++r) {
            *(float4*)xv[r] = *(const float4*)&xs[r0 + r][k4];
            *(float4*)sv[r] = *(const float4*)&ss[r0 + r][k4];
            *(float4*)av[r] = *(const float4*)&as[r0 + r][k4];
        }
        #pragma unroll
        for (int kk = 0; kk < 4; ++kk) {
            int k = k4 + kk;
            float wi[4], wj[4], we[4], ws[4];
            *(float4*)wi = *(const float4*)(Wi    + (size_t)k * DIM + j0);
            *(float4*)wj = *(const float4*)(Wj    + (size_t)k * DIM + j0);
            *(float4*)we = *(const float4*)(We    + (size_t)k * DIM + j0);
            *(float4*)ws = *(const float4*)(Wself + (size_t)k * DIM + j0);
            #pragma unroll
            for (int r = 0; r < 4; ++r) {
                #pragma unroll
                for (int c = 0; c < 4; ++c) {
                    acc_hi[r][c] += xv[r][kk] * wi[c];
                    acc_m [r][c] += xv[r][kk] * ws[c]
                                  + sv[r][kk] * wj[c]
                                  + av[r][kk] * we[c];
                }
            }
        }
    }

    #pragma unroll
    for (int r = 0; r < 4; ++r) {
        int n = n0 + r0 + r;
        if (n >= N) continue;
        float d = dg[r0 + r];
        float4 o;
        o.x = acc_m[r][0] + d * acc_hi[r][0];
        o.y = acc_m[r][1] + d * acc_hi[r][1];
        o.z = acc_m[r][2] + d * acc_hi[r][2];
        o.w = acc_m[r][3] + d * acc_hi[r][3];
        *(float4*)(out + (size_t)n * DIM + j0) = o;
    }
}

extern "C" void kernel_launch(void* const* d_in, const int* in_sizes, int n_in,
                              void* d_out, int out_size, void* d_ws, size_t ws_size,
                              hipStream_t stream)
{
    const float* x     = (const float*)d_in[0];
    const int*   eidx  = (const int*)  d_in[1];
    const float* ew    = (const float*)d_in[2];
    const float* ea    = (const float*)d_in[3];
    const float* Wmsg  = (const float*)d_in[4];
    const float* Wself = (const float*)d_in[5];
    float*       out   = (float*)d_out;

    int N = in_sizes[0] / DIM;
    int E = in_sizes[1] / 2;
    const int* src = eidx;
    const int* dst = eidx + E;

    float* S   = (float*)d_ws;
    float* A   = S + (size_t)N * DIM;
    float* deg = A + (size_t)N * DIM;

    size_t zbytes = ((size_t)2 * N * DIM + N) * sizeof(float);
    hipMemsetAsync(d_ws, 0, zbytes, stream);

    // one wave per edge
    long long total_threads = (long long)E * 64;
    int blocks = (int)((total_threads + 255) / 256);
    edge_scatter<<<blocks, 256, 0, stream>>>(x, src, dst, ew, ea, S, A, deg, E);

    int gblocks = (N + 31) / 32;
    fused_out<<<gblocks, 256, 0, stream>>>(x, S, A, deg, Wmsg, Wself, out, N);
}

// Round 2
// 448.014 us; speedup vs baseline: 2.9442x; 2.9442x over previous
//
#include <hip/hip_runtime.h>

#define DIM 128

// ---------------------------------------------------------------------------
// Phase 1: histogram of dst -> counts[n]
// ---------------------------------------------------------------------------
__global__ __launch_bounds__(256) void k_hist(const int* __restrict__ dst,
                                              int* __restrict__ counts, int E)
{
    int e = blockIdx.x * blockDim.x + threadIdx.x;
    if (e < E) atomicAdd(&counts[dst[e]], 1);
}

// ---------------------------------------------------------------------------
// Phase 2a: per-block (1024-elem) partial sums of counts
// ---------------------------------------------------------------------------
__global__ __launch_bounds__(256) void k_blocksum(const int* __restrict__ counts,
                                                  int* __restrict__ bsums, int N)
{
    __shared__ int sd[256];
    int b = blockIdx.x, t = threadIdx.x;
    int base = b * 1024 + t * 4;
    int s = 0;
    #pragma unroll
    for (int i = 0; i < 4; ++i) {
        int idx = base + i;
        if (idx < N) s += counts[idx];
    }
    sd[t] = s; __syncthreads();
    for (int off = 128; off > 0; off >>= 1) {
        if (t < off) sd[t] += sd[t + off];
        __syncthreads();
    }
    if (t == 0) bsums[b] = sd[0];
}

// ---------------------------------------------------------------------------
// Phase 2b: exclusive scan of block sums (single block; nb <= 256)
// ---------------------------------------------------------------------------
__global__ __launch_bounds__(256) void k_scanb(int* __restrict__ bsums, int nb)
{
    __shared__ int sd[256];
    int t = threadIdx.x;
    int v = (t < nb) ? bsums[t] : 0;
    sd[t] = v; __syncthreads();
    for (int off = 1; off < 256; off <<= 1) {
        int add = (t >= off) ? sd[t - off] : 0;
        __syncthreads();
        sd[t] += add;
        __syncthreads();
    }
    if (t < nb) bsums[t] = sd[t] - v;   // exclusive
}

// ---------------------------------------------------------------------------
// Phase 2c: per-block exclusive scan of counts + block offset -> starts, cursor
// ---------------------------------------------------------------------------
__global__ __launch_bounds__(256) void k_scan(const int* __restrict__ counts,
                                              const int* __restrict__ bsums,
                                              int* __restrict__ starts,
                                              int* __restrict__ cursor,
                                              int N, int E)
{
    __shared__ int sd[256];
    int b = blockIdx.x, t = threadIdx.x;
    int base = b * 1024 + t * 4;
    int c0 = 0, c1 = 0, c2 = 0, c3 = 0;
    if (base     < N) c0 = counts[base];
    if (base + 1 < N) c1 = counts[base + 1];
    if (base + 2 < N) c2 = counts[base + 2];
    if (base + 3 < N) c3 = counts[base + 3];
    int s = c0 + c1 + c2 + c3;
    sd[t] = s; __syncthreads();
    for (int off = 1; off < 256; off <<= 1) {
        int add = (t >= off) ? sd[t - off] : 0;
        __syncthreads();
        sd[t] += add;
        __syncthreads();
    }
    int run = bsums[b] + sd[t] - s;   // exclusive prefix for this thread's chunk
    if (base     < N) { starts[base]     = run; cursor[base]     = run; run += c0; }
    if (base + 1 < N) { starts[base + 1] = run; cursor[base + 1] = run; run += c1; }
    if (base + 2 < N) { starts[base + 2] = run; cursor[base + 2] = run; run += c2; }
    if (base + 3 < N) { starts[base + 3] = run; cursor[base + 3] = run; run += c3; }
    if (b == 0 && t == 0) starts[N] = E;
}

// ---------------------------------------------------------------------------
// Phase 3: bucket fill  elist[start[dst]+k] = e
// ---------------------------------------------------------------------------
__global__ __launch_bounds__(256) void k_fill(const int* __restrict__ dst,
                                              int* __restrict__ cursor,
                                              int* __restrict__ elist, int E)
{
    int e = blockIdx.x * blockDim.x + threadIdx.x;
    if (e < E) {
        int p = atomicAdd(&cursor[dst[e]], 1);
        elist[p] = e;
    }
}

// ---------------------------------------------------------------------------
// Phase 4: one wave per node — accumulate S/A/deg in registers, no atomics.
// ---------------------------------------------------------------------------
__global__ __launch_bounds__(256) void k_node_reduce(
    const float* __restrict__ x,
    const int*   __restrict__ src,
    const float* __restrict__ w,
    const float* __restrict__ ea,
    const int*   __restrict__ starts,
    const int*   __restrict__ elist,
    float* __restrict__ S,
    float* __restrict__ A,
    float* __restrict__ deg,
    int N)
{
    int wid  = (blockIdx.x * blockDim.x + threadIdx.x) >> 6;
    int lane = threadIdx.x & 63;
    if (wid >= N) return;

    int beg = starts[wid];
    int end = starts[wid + 1];

    float2 sacc = {0.f, 0.f};
    float2 aacc = {0.f, 0.f};
    float  wsum = 0.f;

    int i = beg;
    // 2-edge unroll: two independent load chains for memory-level parallelism
    for (; i + 1 < end; i += 2) {
        int e0 = elist[i], e1 = elist[i + 1];
        int s0 = src[e0],  s1 = src[e1];
        float w0 = w[e0],  w1 = w[e1];
        float2 x0 = *(const float2*)(x  + (size_t)s0 * DIM + lane * 2);
        float2 x1 = *(const float2*)(x  + (size_t)s1 * DIM + lane * 2);
        float2 v0 = *(const float2*)(ea + (size_t)e0 * DIM + lane * 2);
        float2 v1 = *(const float2*)(ea + (size_t)e1 * DIM + lane * 2);
        sacc.x += w0 * x0.x + w1 * x1.x;
        sacc.y += w0 * x0.y + w1 * x1.y;
        aacc.x += w0 * v0.x + w1 * v1.x;
        aacc.y += w0 * v0.y + w1 * v1.y;
        wsum   += w0 + w1;
    }
    if (i < end) {
        int e0 = elist[i];
        int s0 = src[e0];
        float w0 = w[e0];
        float2 x0 = *(const float2*)(x  + (size_t)s0 * DIM + lane * 2);
        float2 v0 = *(const float2*)(ea + (size_t)e0 * DIM + lane * 2);
        sacc.x += w0 * x0.x; sacc.y += w0 * x0.y;
        aacc.x += w0 * v0.x; aacc.y += w0 * v0.y;
        wsum   += w0;
    }

    *(float2*)(S + (size_t)wid * DIM + lane * 2) = sacc;
    *(float2*)(A + (size_t)wid * DIM + lane * 2) = aacc;
    if (lane == 0) deg[wid] = wsum;
}

// ---------------------------------------------------------------------------
// Phase 5: out[n] = deg[n]*(x@W_i)[n] + (x@W_self)[n] + (S@W_j)[n] + (A@W_e)[n]
// Block: 256 threads -> 32 nodes x 128 cols, 4x4 register tile per thread.
// ---------------------------------------------------------------------------
__global__ __launch_bounds__(256) void fused_out(
    const float* __restrict__ x,
    const float* __restrict__ S,
    const float* __restrict__ A,
    const float* __restrict__ deg,
    const float* __restrict__ Wmsg,   // [384][128]: rows 0-127 Wi, 128-255 Wj, 256-383 We
    const float* __restrict__ Wself,  // [128][128]
    float* __restrict__ out,
    int N)
{
    __shared__ float xs[32][DIM];
    __shared__ float ss[32][DIM];
    __shared__ float as[32][DIM];
    __shared__ float dg[32];

    int t  = threadIdx.x;
    int n0 = blockIdx.x * 32;

    #pragma unroll
    for (int i = 0; i < 4; ++i) {
        int l  = i * 256 + t;
        int n  = l >> 5;
        int k4 = (l & 31) << 2;
        if (n0 + n < N) {
            *(float4*)&xs[n][k4] = *(const float4*)(x + (size_t)(n0 + n) * DIM + k4);
            *(float4*)&ss[n][k4] = *(const float4*)(S + (size_t)(n0 + n) * DIM + k4);
            *(float4*)&as[n][k4] = *(const float4*)(A + (size_t)(n0 + n) * DIM + k4);
        } else {
            float4 z = {0.f, 0.f, 0.f, 0.f};
            *(float4*)&xs[n][k4] = z;
            *(float4*)&ss[n][k4] = z;
            *(float4*)&as[n][k4] = z;
        }
    }
    if (t < 32) dg[t] = (n0 + t < N) ? deg[n0 + t] : 0.f;
    __syncthreads();

    int tx = t & 31;
    int ty = t >> 5;
    int j0 = tx * 4;
    int r0 = ty * 4;

    float acc_hi[4][4] = {{0.f}};
    float acc_m [4][4] = {{0.f}};

    const float* Wi = Wmsg;
    const float* Wj = Wmsg + 128 * DIM;
    const float* We = Wmsg + 256 * DIM;

    for (int k4 = 0; k4 < DIM; k4 += 4) {
        float xv[4][4], sv[4][4], av[4][4];
        #pragma unroll
        for (int r = 0; r < 4; ++r) {
            *(float4*)xv[r] = *(const float4*)&xs[r0 + r][k4];
            *(float4*)sv[r] = *(const float4*)&ss[r0 + r][k4];
            *(float4*)av[r] = *(const float4*)&as[r0 + r][k4];
        }
        #pragma unroll
        for (int kk = 0; kk < 4; ++kk) {
            int k = k4 + kk;
            float wi[4], wj[4], we[4], ws[4];
            *(float4*)wi = *(const float4*)(Wi    + (size_t)k * DIM + j0);
            *(float4*)wj = *(const float4*)(Wj    + (size_t)k * DIM + j0);
            *(float4*)we = *(const float4*)(We    + (size_t)k * DIM + j0);
            *(float4*)ws = *(const float4*)(Wself + (size_t)k * DIM + j0);
            #pragma unroll
            for (int r = 0; r < 4; ++r) {
                #pragma unroll
                for (int c = 0; c < 4; ++c) {
                    acc_hi[r][c] += xv[r][kk] * wi[c];
                    acc_m [r][c] += xv[r][kk] * ws[c]
                                  + sv[r][kk] * wj[c]
                                  + av[r][kk] * we[c];
                }
            }
        }
    }

    #pragma unroll
    for (int r = 0; r < 4; ++r) {
        int n = n0 + r0 + r;
        if (n >= N) continue;
        float d = dg[r0 + r];
        float4 o;
        o.x = acc_m[r][0] + d * acc_hi[r][0];
        o.y = acc_m[r][1] + d * acc_hi[r][1];
        o.z = acc_m[r][2] + d * acc_hi[r][2];
        o.w = acc_m[r][3] + d * acc_hi[r][3];
        *(float4*)(out + (size_t)n * DIM + j0) = o;
    }
}

extern "C" void kernel_launch(void* const* d_in, const int* in_sizes, int n_in,
                              void* d_out, int out_size, void* d_ws, size_t ws_size,
                              hipStream_t stream)
{
    const float* x     = (const float*)d_in[0];
    const int*   eidx  = (const int*)  d_in[1];
    const float* ew    = (const float*)d_in[2];
    const float* ea    = (const float*)d_in[3];
    const float* Wmsg  = (const float*)d_in[4];
    const float* Wself = (const float*)d_in[5];
    float*       out   = (float*)d_out;

    int N = in_sizes[0] / DIM;
    int E = in_sizes[1] / 2;
    const int* src = eidx;
    const int* dst = eidx + E;

    // ---- workspace layout ----
    float* S      = (float*)d_ws;                 // N*128 f
    float* A      = S + (size_t)N * DIM;          // N*128 f
    float* deg    = A + (size_t)N * DIM;          // N f
    int*   counts = (int*)(deg + N);              // N i
    int*   starts = counts + N;                   // N+1 i
    int*   cursor = starts + N + 1;               // N i
    int*   bsums  = cursor + N;                   // 256 i
    int*   elist  = bsums + 256;                  // E i

    int nb = (N + 1023) / 1024;                   // blocks for scan (<=256)

    hipMemsetAsync(counts, 0, (size_t)N * sizeof(int), stream);

    int eblocks = (E + 255) / 256;
    k_hist<<<eblocks, 256, 0, stream>>>(dst, counts, E);
    k_blocksum<<<nb, 256, 0, stream>>>(counts, bsums, N);
    k_scanb<<<1, 256, 0, stream>>>(bsums, nb);
    k_scan<<<nb, 256, 0, stream>>>(counts, bsums, starts, cursor, N, E);
    k_fill<<<eblocks, 256, 0, stream>>>(dst, cursor, elist, E);

    long long rthreads = (long long)N * 64;
    int rblocks = (int)((rthreads + 255) / 256);
    k_node_reduce<<<rblocks, 256, 0, stream>>>(x, src, ew, ea, starts, elist,
                                               S, A, deg, N);

    int gblocks = (N + 31) / 32;
    fused_out<<<gblocks, 256, 0, stream>>>(x, S, A, deg, Wmsg, Wself, out, N);
}

// Round 3
// 257.950 us; speedup vs baseline: 5.1136x; 1.7368x over previous
//
#include <hip/hip_runtime.h>

#define DIM 128

typedef __attribute__((ext_vector_type(8))) short short8;
typedef __attribute__((ext_vector_type(4))) float f32x4;

__device__ inline unsigned short f2bf(float f) {
    unsigned int u = __builtin_bit_cast(unsigned int, f);
    unsigned int r = (u + 0x7FFFu + ((u >> 16) & 1u)) >> 16;   // RNE
    return (unsigned short)r;
}

// ---------------------------------------------------------------------------
// Phase 1: histogram of dst -> counts[n]
// ---------------------------------------------------------------------------
__global__ __launch_bounds__(256) void k_hist(const int* __restrict__ dst,
                                              int* __restrict__ counts, int E)
{
    int e = blockIdx.x * blockDim.x + threadIdx.x;
    if (e < E) atomicAdd(&counts[dst[e]], 1);
}

// ---------------------------------------------------------------------------
// Phase 2a: per-block (1024-elem) partial sums of counts
// ---------------------------------------------------------------------------
__global__ __launch_bounds__(256) void k_blocksum(const int* __restrict__ counts,
                                                  int* __restrict__ bsums, int N)
{
    __shared__ int sd[256];
    int b = blockIdx.x, t = threadIdx.x;
    int base = b * 1024 + t * 4;
    int s = 0;
    #pragma unroll
    for (int i = 0; i < 4; ++i) {
        int idx = base + i;
        if (idx < N) s += counts[idx];
    }
    sd[t] = s; __syncthreads();
    for (int off = 128; off > 0; off >>= 1) {
        if (t < off) sd[t] += sd[t + off];
        __syncthreads();
    }
    if (t == 0) bsums[b] = sd[0];
}

// ---------------------------------------------------------------------------
// Phase 2b: exclusive scan of block sums (single block; nb <= 256)
// ---------------------------------------------------------------------------
__global__ __launch_bounds__(256) void k_scanb(int* __restrict__ bsums, int nb)
{
    __shared__ int sd[256];
    int t = threadIdx.x;
    int v = (t < nb) ? bsums[t] : 0;
    sd[t] = v; __syncthreads();
    for (int off = 1; off < 256; off <<= 1) {
        int add = (t >= off) ? sd[t - off] : 0;
        __syncthreads();
        sd[t] += add;
        __syncthreads();
    }
    if (t < nb) bsums[t] = sd[t] - v;   // exclusive
}

// ---------------------------------------------------------------------------
// Phase 2c: per-block exclusive scan of counts + block offset -> starts, cursor
// ---------------------------------------------------------------------------
__global__ __launch_bounds__(256) void k_scan(const int* __restrict__ counts,
                                              const int* __restrict__ bsums,
                                              int* __restrict__ starts,
                                              int* __restrict__ cursor,
                                              int N, int E)
{
    __shared__ int sd[256];
    int b = blockIdx.x, t = threadIdx.x;
    int base = b * 1024 + t * 4;
    int c0 = 0, c1 = 0, c2 = 0, c3 = 0;
    if (base     < N) c0 = counts[base];
    if (base + 1 < N) c1 = counts[base + 1];
    if (base + 2 < N) c2 = counts[base + 2];
    if (base + 3 < N) c3 = counts[base + 3];
    int s = c0 + c1 + c2 + c3;
    sd[t] = s; __syncthreads();
    for (int off = 1; off < 256; off <<= 1) {
        int add = (t >= off) ? sd[t - off] : 0;
        __syncthreads();
        sd[t] += add;
        __syncthreads();
    }
    int run = bsums[b] + sd[t] - s;
    if (base     < N) { starts[base]     = run; cursor[base]     = run; run += c0; }
    if (base + 1 < N) { starts[base + 1] = run; cursor[base + 1] = run; run += c1; }
    if (base + 2 < N) { starts[base + 2] = run; cursor[base + 2] = run; run += c2; }
    if (base + 3 < N) { starts[base + 3] = run; cursor[base + 3] = run; run += c3; }
    if (b == 0 && t == 0) starts[N] = E;
}

// ---------------------------------------------------------------------------
// Phase 3: bucket fill  elist[start[dst]+k] = e
// ---------------------------------------------------------------------------
__global__ __launch_bounds__(256) void k_fill(const int* __restrict__ dst,
                                              int* __restrict__ cursor,
                                              int* __restrict__ elist, int E)
{
    int e = blockIdx.x * blockDim.x + threadIdx.x;
    if (e < E) {
        int p = atomicAdd(&cursor[dst[e]], 1);
        elist[p] = e;
    }
}

// ---------------------------------------------------------------------------
// Phase 4: one wave per node — accumulate S/A/deg in registers, emit the
// bf16 Xcat row: [deg*x | x | S | A]  (512 bf16 per node).
// ---------------------------------------------------------------------------
__global__ __launch_bounds__(256) void k_node_reduce(
    const float* __restrict__ x,
    const int*   __restrict__ src,
    const float* __restrict__ w,
    const float* __restrict__ ea,
    const int*   __restrict__ starts,
    const int*   __restrict__ elist,
    unsigned short* __restrict__ Xcat,   // [Npad][512] bf16
    int N)
{
    int wid  = (blockIdx.x * blockDim.x + threadIdx.x) >> 6;
    int lane = threadIdx.x & 63;
    if (wid >= N) return;

    int beg = starts[wid];
    int end = starts[wid + 1];

    float2 sacc = {0.f, 0.f};
    float2 aacc = {0.f, 0.f};
    float  wsum = 0.f;

    int i = beg;
    for (; i + 1 < end; i += 2) {
        int e0 = elist[i], e1 = elist[i + 1];
        int s0 = src[e0],  s1 = src[e1];
        float w0 = w[e0],  w1 = w[e1];
        float2 x0 = *(const float2*)(x  + (size_t)s0 * DIM + lane * 2);
        float2 x1 = *(const float2*)(x  + (size_t)s1 * DIM + lane * 2);
        float2 v0 = *(const float2*)(ea + (size_t)e0 * DIM + lane * 2);
        float2 v1 = *(const float2*)(ea + (size_t)e1 * DIM + lane * 2);
        sacc.x += w0 * x0.x + w1 * x1.x;
        sacc.y += w0 * x0.y + w1 * x1.y;
        aacc.x += w0 * v0.x + w1 * v1.x;
        aacc.y += w0 * v0.y + w1 * v1.y;
        wsum   += w0 + w1;
    }
    if (i < end) {
        int e0 = elist[i];
        int s0 = src[e0];
        float w0 = w[e0];
        float2 x0 = *(const float2*)(x  + (size_t)s0 * DIM + lane * 2);
        float2 v0 = *(const float2*)(ea + (size_t)e0 * DIM + lane * 2);
        sacc.x += w0 * x0.x; sacc.y += w0 * x0.y;
        aacc.x += w0 * v0.x; aacc.y += w0 * v0.y;
        wsum   += w0;
    }

    float2 xv = *(const float2*)(x + (size_t)wid * DIM + lane * 2);

    unsigned short* row = Xcat + (size_t)wid * 512;
    ushort2 o;
    o.x = f2bf(wsum * xv.x); o.y = f2bf(wsum * xv.y);
    *(ushort2*)(row +       lane * 2) = o;                 // deg*x -> W_i
    o.x = f2bf(xv.x);        o.y = f2bf(xv.y);
    *(ushort2*)(row + 128 + lane * 2) = o;                 // x     -> W_self
    o.x = f2bf(sacc.x);      o.y = f2bf(sacc.y);
    *(ushort2*)(row + 256 + lane * 2) = o;                 // S     -> W_j
    o.x = f2bf(aacc.x);      o.y = f2bf(aacc.y);
    *(ushort2*)(row + 384 + lane * 2) = o;                 // A     -> W_e
}

// ---------------------------------------------------------------------------
// Phase 5a: weights -> bf16, transposed to Bt[n][k], k-concat order matching
// Xcat: k 0-127 = W_i, 128-255 = W_self, 256-383 = W_j, 384-511 = W_e.
// ---------------------------------------------------------------------------
__global__ __launch_bounds__(256) void k_wcvt(const float* __restrict__ Wmsg,
                                              const float* __restrict__ Wself,
                                              unsigned short* __restrict__ Bt)
{
    int idx = blockIdx.x * blockDim.x + threadIdx.x;   // 0 .. 128*512-1
    if (idx >= 128 * 512) return;
    int n = idx >> 9;
    int k = idx & 511;
    float v;
    if (k < 128)      v = Wmsg [(size_t)k * DIM + n];          // W_i
    else if (k < 256) v = Wself[(size_t)(k - 128) * DIM + n];  // W_self
    else              v = Wmsg [(size_t)(k - 128) * DIM + n];  // W_j (256-383), W_e (384-511)
    Bt[(size_t)n * 512 + k] = f2bf(v);
}

// ---------------------------------------------------------------------------
// Phase 5b: MFMA GEMM  out[Npad x 128] = Xcat[Npad x 512] @ Bt^T
// 128x128 tile, BK=64, 4 waves x (4x4 frags of 16x16x32 bf16),
// double-buffered XOR-swizzled LDS, 1 barrier per K-step.
// ---------------------------------------------------------------------------
__global__ __launch_bounds__(256) void k_gemm(
    const unsigned short* __restrict__ Xcat,  // [Npad][512]
    const unsigned short* __restrict__ Bt,    // [128][512]
    float* __restrict__ out, int N)
{
    __shared__ unsigned short As[2][128 * 64];
    __shared__ unsigned short Bs[2][128 * 64];

    int t    = threadIdx.x;
    int lane = t & 63;
    int w    = t >> 6;
    int wr   = w >> 1, wc = w & 1;
    int row0 = blockIdx.x * 128;

    int lr = t >> 3;          // 0..31: row within a 32-row round
    int lc = (t & 7) * 8;     // col in bf16 units (16B granules)

    f32x4 acc[4][4];
    #pragma unroll
    for (int m = 0; m < 4; ++m)
        #pragma unroll
        for (int n = 0; n < 4; ++n)
            acc[m][n] = (f32x4){0.f, 0.f, 0.f, 0.f};

    uint4 ar[4], br[4];

    // prologue: stage K-tile 0
    #pragma unroll
    for (int r = 0; r < 4; ++r) {
        int row = r * 32 + lr;
        ar[r] = *(const uint4*)(Xcat + (size_t)(row0 + row) * 512 + lc);
        br[r] = *(const uint4*)(Bt   + (size_t)row * 512 + lc);
    }
    #pragma unroll
    for (int r = 0; r < 4; ++r) {
        int row = r * 32 + lr;
        int sidx = row * 64 + (lc ^ ((row & 7) << 3));
        *(uint4*)&As[0][sidx] = ar[r];
        *(uint4*)&Bs[0][sidx] = br[r];
    }
    __syncthreads();

    for (int kt = 0; kt < 8; ++kt) {
        int cur = kt & 1;
        if (kt < 7) {
            int k0 = (kt + 1) * 64;
            #pragma unroll
            for (int r = 0; r < 4; ++r) {
                int row = r * 32 + lr;
                ar[r] = *(const uint4*)(Xcat + (size_t)(row0 + row) * 512 + k0 + lc);
                br[r] = *(const uint4*)(Bt   + (size_t)row * 512 + k0 + lc);
            }
        }

        #pragma unroll
        for (int kk = 0; kk < 2; ++kk) {
            short8 a[4], b[4];
            int colb = kk * 32 + (lane >> 4) * 8;
            #pragma unroll
            for (int mm = 0; mm < 4; ++mm) {
                int row = wr * 64 + mm * 16 + (lane & 15);
                a[mm] = *(const short8*)&As[cur][row * 64 + (colb ^ ((row & 7) << 3))];
            }
            #pragma unroll
            for (int nn = 0; nn < 4; ++nn) {
                int row = wc * 64 + nn * 16 + (lane & 15);
                b[nn] = *(const short8*)&Bs[cur][row * 64 + (colb ^ ((row & 7) << 3))];
            }
            #pragma unroll
            for (int mm = 0; mm < 4; ++mm)
                #pragma unroll
                for (int nn = 0; nn < 4; ++nn)
                    acc[mm][nn] = __builtin_amdgcn_mfma_f32_16x16x32_bf16(
                        a[mm], b[nn], acc[mm][nn], 0, 0, 0);
        }

        if (kt < 7) {
            int nxt = cur ^ 1;
            #pragma unroll
            for (int r = 0; r < 4; ++r) {
                int row = r * 32 + lr;
                int sidx = row * 64 + (lc ^ ((row & 7) << 3));
                *(uint4*)&As[nxt][sidx] = ar[r];
                *(uint4*)&Bs[nxt][sidx] = br[r];
            }
            __syncthreads();
        }
    }

    // C write: col = lane&15, row = (lane>>4)*4 + j  (verified gfx950 layout)
    #pragma unroll
    for (int mm = 0; mm < 4; ++mm) {
        #pragma unroll
        for (int j = 0; j < 4; ++j) {
            int m = row0 + wr * 64 + mm * 16 + (lane >> 4) * 4 + j;
            if (m >= N) continue;
            #pragma unroll
            for (int nn = 0; nn < 4; ++nn) {
                int c = wc * 64 + nn * 16 + (lane & 15);
                out[(size_t)m * DIM + c] = acc[mm][nn][j];
            }
        }
    }
}

extern "C" void kernel_launch(void* const* d_in, const int* in_sizes, int n_in,
                              void* d_out, int out_size, void* d_ws, size_t ws_size,
                              hipStream_t stream)
{
    const float* x     = (const float*)d_in[0];
    const int*   eidx  = (const int*)  d_in[1];
    const float* ew    = (const float*)d_in[2];
    const float* ea    = (const float*)d_in[3];
    const float* Wmsg  = (const float*)d_in[4];
    const float* Wself = (const float*)d_in[5];
    float*       out   = (float*)d_out;

    int N = in_sizes[0] / DIM;
    int E = in_sizes[1] / 2;
    int Npad = (N + 127) & ~127;
    const int* src = eidx;
    const int* dst = eidx + E;

    // ---- workspace layout ----
    unsigned short* Xcat = (unsigned short*)d_ws;          // Npad*512 bf16
    unsigned short* Bt   = Xcat + (size_t)Npad * 512;      // 128*512 bf16
    int* counts = (int*)(Bt + 128 * 512);                  // N
    int* starts = counts + N;                              // N+1
    int* cursor = starts + N + 1;                          // N
    int* bsums  = cursor + N;                              // 256
    int* elist  = bsums + 256;                             // E

    int nb = (N + 1023) / 1024;

    hipMemsetAsync(counts, 0, (size_t)N * sizeof(int), stream);

    int eblocks = (E + 255) / 256;
    k_hist<<<eblocks, 256, 0, stream>>>(dst, counts, E);
    k_blocksum<<<nb, 256, 0, stream>>>(counts, bsums, N);
    k_scanb<<<1, 256, 0, stream>>>(bsums, nb);
    k_scan<<<nb, 256, 0, stream>>>(counts, bsums, starts, cursor, N, E);
    k_fill<<<eblocks, 256, 0, stream>>>(dst, cursor, elist, E);

    long long rthreads = (long long)N * 64;
    int rblocks = (int)((rthreads + 255) / 256);
    k_node_reduce<<<rblocks, 256, 0, stream>>>(x, src, ew, ea, starts, elist,
                                               Xcat, N);

    k_wcvt<<<(128 * 512 + 255) / 256, 256, 0, stream>>>(Wmsg, Wself, Bt);

    k_gemm<<<Npad / 128, 256, 0, stream>>>(Xcat, Bt, out, N);
}

// Round 4
// 257.613 us; speedup vs baseline: 5.1202x; 1.0013x over previous
//
#include <hip/hip_runtime.h>

#define DIM 128

typedef __attribute__((ext_vector_type(8))) short short8;
typedef __attribute__((ext_vector_type(4))) float f32x4;

__device__ inline unsigned short f2bf(float f) {
    unsigned int u = __builtin_bit_cast(unsigned int, f);
    unsigned int r = (u + 0x7FFFu + ((u >> 16) & 1u)) >> 16;   // RNE
    return (unsigned short)r;
}
__device__ inline unsigned int packbf2(float a, float b) {
    return (unsigned int)f2bf(a) | ((unsigned int)f2bf(b) << 16);
}

// ---------------------------------------------------------------------------
// Phase 0: zero the counts array (replaces pathological graph hipMemsetAsync)
// ---------------------------------------------------------------------------
__global__ __launch_bounds__(256) void k_zero(int* __restrict__ p, int n)
{
    int i = blockIdx.x * blockDim.x + threadIdx.x;
    if (i < n) p[i] = 0;
}

// ---------------------------------------------------------------------------
// Phase 1: histogram of dst -> counts[n]
// ---------------------------------------------------------------------------
__global__ __launch_bounds__(256) void k_hist(const int* __restrict__ dst,
                                              int* __restrict__ counts, int E)
{
    int e = blockIdx.x * blockDim.x + threadIdx.x;
    if (e < E) atomicAdd(&counts[dst[e]], 1);
}

// ---------------------------------------------------------------------------
// Phase 2a: per-block (1024-elem) partial sums of counts
// ---------------------------------------------------------------------------
__global__ __launch_bounds__(256) void k_blocksum(const int* __restrict__ counts,
                                                  int* __restrict__ bsums, int N)
{
    __shared__ int sd[256];
    int b = blockIdx.x, t = threadIdx.x;
    int base = b * 1024 + t * 4;
    int s = 0;
    #pragma unroll
    for (int i = 0; i < 4; ++i) {
        int idx = base + i;
        if (idx < N) s += counts[idx];
    }
    sd[t] = s; __syncthreads();
    for (int off = 128; off > 0; off >>= 1) {
        if (t < off) sd[t] += sd[t + off];
        __syncthreads();
    }
    if (t == 0) bsums[b] = sd[0];
}

// ---------------------------------------------------------------------------
// Phase 2b: exclusive scan of block sums (single block; nb <= 256)
// ---------------------------------------------------------------------------
__global__ __launch_bounds__(256) void k_scanb(int* __restrict__ bsums, int nb)
{
    __shared__ int sd[256];
    int t = threadIdx.x;
    int v = (t < nb) ? bsums[t] : 0;
    sd[t] = v; __syncthreads();
    for (int off = 1; off < 256; off <<= 1) {
        int add = (t >= off) ? sd[t - off] : 0;
        __syncthreads();
        sd[t] += add;
        __syncthreads();
    }
    if (t < nb) bsums[t] = sd[t] - v;   // exclusive
}

// ---------------------------------------------------------------------------
// Phase 2c: per-block exclusive scan of counts + block offset -> starts, cursor
// ---------------------------------------------------------------------------
__global__ __launch_bounds__(256) void k_scan(const int* __restrict__ counts,
                                              const int* __restrict__ bsums,
                                              int* __restrict__ starts,
                                              int* __restrict__ cursor,
                                              int N, int E)
{
    __shared__ int sd[256];
    int b = blockIdx.x, t = threadIdx.x;
    int base = b * 1024 + t * 4;
    int c0 = 0, c1 = 0, c2 = 0, c3 = 0;
    if (base     < N) c0 = counts[base];
    if (base + 1 < N) c1 = counts[base + 1];
    if (base + 2 < N) c2 = counts[base + 2];
    if (base + 3 < N) c3 = counts[base + 3];
    int s = c0 + c1 + c2 + c3;
    sd[t] = s; __syncthreads();
    for (int off = 1; off < 256; off <<= 1) {
        int add = (t >= off) ? sd[t - off] : 0;
        __syncthreads();
        sd[t] += add;
        __syncthreads();
    }
    int run = bsums[b] + sd[t] - s;
    if (base     < N) { starts[base]     = run; cursor[base]     = run; run += c0; }
    if (base + 1 < N) { starts[base + 1] = run; cursor[base + 1] = run; run += c1; }
    if (base + 2 < N) { starts[base + 2] = run; cursor[base + 2] = run; run += c2; }
    if (base + 3 < N) { starts[base + 3] = run; cursor[base + 3] = run; run += c3; }
    if (b == 0 && t == 0) starts[N] = E;
}

// ---------------------------------------------------------------------------
// Phase 3: bucket fill  elist[start[dst]+k] = e
// ---------------------------------------------------------------------------
__global__ __launch_bounds__(256) void k_fill(const int* __restrict__ dst,
                                              int* __restrict__ cursor,
                                              int* __restrict__ elist, int E)
{
    int e = blockIdx.x * blockDim.x + threadIdx.x;
    if (e < E) {
        int p = atomicAdd(&cursor[dst[e]], 1);
        elist[p] = e;
    }
}

// ---------------------------------------------------------------------------
// Phase 4: one wave per node — accumulate S/A/deg in registers, emit bf16
// SA row [S | A] (256 bf16) + deg (fp32).
// ---------------------------------------------------------------------------
__global__ __launch_bounds__(256) void k_node_reduce(
    const float* __restrict__ x,
    const int*   __restrict__ src,
    const float* __restrict__ w,
    const float* __restrict__ ea,
    const int*   __restrict__ starts,
    const int*   __restrict__ elist,
    unsigned short* __restrict__ SA,   // [N][256] bf16
    float* __restrict__ deg,           // [N]
    int N)
{
    int wid  = (blockIdx.x * blockDim.x + threadIdx.x) >> 6;
    int lane = threadIdx.x & 63;
    if (wid >= N) return;

    int beg = starts[wid];
    int end = starts[wid + 1];

    float2 sacc = {0.f, 0.f};
    float2 aacc = {0.f, 0.f};
    float  wsum = 0.f;

    int i = beg;
    for (; i + 1 < end; i += 2) {
        int e0 = elist[i], e1 = elist[i + 1];
        int s0 = src[e0],  s1 = src[e1];
        float w0 = w[e0],  w1 = w[e1];
        float2 x0 = *(const float2*)(x  + (size_t)s0 * DIM + lane * 2);
        float2 x1 = *(const float2*)(x  + (size_t)s1 * DIM + lane * 2);
        float2 v0 = *(const float2*)(ea + (size_t)e0 * DIM + lane * 2);
        float2 v1 = *(const float2*)(ea + (size_t)e1 * DIM + lane * 2);
        sacc.x += w0 * x0.x + w1 * x1.x;
        sacc.y += w0 * x0.y + w1 * x1.y;
        aacc.x += w0 * v0.x + w1 * v1.x;
        aacc.y += w0 * v0.y + w1 * v1.y;
        wsum   += w0 + w1;
    }
    if (i < end) {
        int e0 = elist[i];
        int s0 = src[e0];
        float w0 = w[e0];
        float2 x0 = *(const float2*)(x  + (size_t)s0 * DIM + lane * 2);
        float2 v0 = *(const float2*)(ea + (size_t)e0 * DIM + lane * 2);
        sacc.x += w0 * x0.x; sacc.y += w0 * x0.y;
        aacc.x += w0 * v0.x; aacc.y += w0 * v0.y;
        wsum   += w0;
    }

    unsigned short* row = SA + (size_t)wid * 256;
    ushort2 o;
    o.x = f2bf(sacc.x); o.y = f2bf(sacc.y);
    *(ushort2*)(row +       lane * 2) = o;                 // S -> W_j
    o.x = f2bf(aacc.x); o.y = f2bf(aacc.y);
    *(ushort2*)(row + 128 + lane * 2) = o;                 // A -> W_e
    if (lane == 0) deg[wid] = wsum;
}

// ---------------------------------------------------------------------------
// Phase 5a: weights -> bf16, transposed to Bt[n][k].
// k: 0-127 = W_i, 128-255 = W_self, 256-383 = W_j, 384-511 = W_e.
// ---------------------------------------------------------------------------
__global__ __launch_bounds__(256) void k_wcvt(const float* __restrict__ Wmsg,
                                              const float* __restrict__ Wself,
                                              unsigned short* __restrict__ Bt)
{
    int idx = blockIdx.x * blockDim.x + threadIdx.x;
    if (idx >= 128 * 512) return;
    int n = idx >> 9;
    int k = idx & 511;
    float v;
    if (k < 128)      v = Wmsg [(size_t)k * DIM + n];          // W_i
    else if (k < 256) v = Wself[(size_t)(k - 128) * DIM + n];  // W_self
    else              v = Wmsg [(size_t)(k - 128) * DIM + n];  // W_j, W_e
    Bt[(size_t)n * 512 + k] = f2bf(v);
}

// ---------------------------------------------------------------------------
// Phase 5b: MFMA GEMM  out = [deg*x | x | S | A] @ Bt^T, A-operand K-chunks
// 0-1 = deg*x (staged from fp32 x), 2-3 = x, 4-7 = SA. B frags read directly
// from global (Bt is 128 KB, L2-resident). Single acc, 8 K-steps, bk = s*64.
// ---------------------------------------------------------------------------
__global__ __launch_bounds__(256) void k_gemm(
    const float* __restrict__ x,             // [N][128] fp32
    const unsigned short* __restrict__ SA,   // [N][256] bf16
    const unsigned short* __restrict__ Bt,   // [128][512] bf16
    const float* __restrict__ deg,           // [N]
    float* __restrict__ out, int N)
{
    __shared__ unsigned short As[2][128 * 64];
    __shared__ float dgs[128];

    int t    = threadIdx.x;
    int lane = t & 63;
    int w    = t >> 6;
    int wr   = w >> 1, wc = w & 1;
    int row0 = blockIdx.x * 128;
    int lr   = t >> 3;          // 0..31
    int lc   = (t & 7) * 8;     // bf16 units

    if (t < 128) {
        int g = row0 + t;
        dgs[t] = (g < N) ? deg[g] : 0.f;
    }
    __syncthreads();

    f32x4 acc[4][4];
    #pragma unroll
    for (int m = 0; m < 4; ++m)
        #pragma unroll
        for (int n = 0; n < 4; ++n)
            acc[m][n] = (f32x4){0.f, 0.f, 0.f, 0.f};

    float4 fa[4], fb[4];

    // prologue: stage step 0 (deg*x, x-cols 0-63)
    #pragma unroll
    for (int r = 0; r < 4; ++r) {
        int row = r * 32 + lr;
        int g = row0 + row; if (g >= N) g = N - 1;
        const float* xp = x + (size_t)g * DIM + lc;
        fa[r] = *(const float4*)xp;
        fb[r] = *(const float4*)(xp + 4);
    }
    #pragma unroll
    for (int r = 0; r < 4; ++r) {
        int row = r * 32 + lr;
        float d = dgs[row];
        uint4 u;
        u.x = packbf2(d * fa[r].x, d * fa[r].y);
        u.y = packbf2(d * fa[r].z, d * fa[r].w);
        u.z = packbf2(d * fb[r].x, d * fb[r].y);
        u.w = packbf2(d * fb[r].z, d * fb[r].w);
        *(uint4*)&As[0][row * 64 + (lc ^ ((row & 7) << 3))] = u;
    }
    __syncthreads();

    for (int s = 0; s < 8; ++s) {
        int cur = s & 1;
        int sn  = s + 1;

        // prefetch step sn into registers
        if (sn < 8) {
            if (sn < 4) {
                int k0 = (sn & 1) * 64;   // sn=1->64, 2->0, 3->64
                #pragma unroll
                for (int r = 0; r < 4; ++r) {
                    int row = r * 32 + lr;
                    int g = row0 + row; if (g >= N) g = N - 1;
                    const float* xp = x + (size_t)g * DIM + k0 + lc;
                    fa[r] = *(const float4*)xp;
                    fb[r] = *(const float4*)(xp + 4);
                }
            } else {
                int k0 = (sn - 4) * 64;
                #pragma unroll
                for (int r = 0; r < 4; ++r) {
                    int row = r * 32 + lr;
                    int g = row0 + row; if (g >= N) g = N - 1;
                    fa[r] = *(const float4*)(SA + (size_t)g * 256 + k0 + lc);
                }
            }
        }

        // compute step s: A from LDS, B frags direct from global (L2)
        int bk = s * 64;
        #pragma unroll
        for (int kk = 0; kk < 2; ++kk) {
            int colb = kk * 32 + (lane >> 4) * 8;
            short8 a[4], b[4];
            #pragma unroll
            for (int mm = 0; mm < 4; ++mm) {
                int row = wr * 64 + mm * 16 + (lane & 15);
                a[mm] = *(const short8*)&As[cur][row * 64 + (colb ^ ((row & 7) << 3))];
            }
            int ck = bk + colb;
            #pragma unroll
            for (int nn = 0; nn < 4; ++nn) {
                int n = wc * 64 + nn * 16 + (lane & 15);
                b[nn] = *(const short8*)(Bt + (size_t)n * 512 + ck);
            }
            #pragma unroll
            for (int mm = 0; mm < 4; ++mm)
                #pragma unroll
                for (int nn = 0; nn < 4; ++nn)
                    acc[mm][nn] = __builtin_amdgcn_mfma_f32_16x16x32_bf16(
                        a[mm], b[nn], acc[mm][nn], 0, 0, 0);
        }

        // write prefetched step sn to the other LDS buffer
        if (sn < 8) {
            int nxt = cur ^ 1;
            #pragma unroll
            for (int r = 0; r < 4; ++r) {
                int row = r * 32 + lr;
                uint4 u;
                if (sn < 2) {
                    float d = dgs[row];
                    u.x = packbf2(d * fa[r].x, d * fa[r].y);
                    u.y = packbf2(d * fa[r].z, d * fa[r].w);
                    u.z = packbf2(d * fb[r].x, d * fb[r].y);
                    u.w = packbf2(d * fb[r].z, d * fb[r].w);
                } else if (sn < 4) {
                    u.x = packbf2(fa[r].x, fa[r].y);
                    u.y = packbf2(fa[r].z, fa[r].w);
                    u.z = packbf2(fb[r].x, fb[r].y);
                    u.w = packbf2(fb[r].z, fb[r].w);
                } else {
                    u = __builtin_bit_cast(uint4, fa[r]);
                }
                *(uint4*)&As[nxt][row * 64 + (lc ^ ((row & 7) << 3))] = u;
            }
            __syncthreads();
        }
    }

    // C write: col = lane&15, row = (lane>>4)*4 + j
    #pragma unroll
    for (int mm = 0; mm < 4; ++mm) {
        #pragma unroll
        for (int j = 0; j < 4; ++j) {
            int m  = wr * 64 + mm * 16 + (lane >> 4) * 4 + j;
            int gm = row0 + m;
            if (gm >= N) continue;
            #pragma unroll
            for (int nn = 0; nn < 4; ++nn) {
                int c = wc * 64 + nn * 16 + (lane & 15);
                out[(size_t)gm * DIM + c] = acc[mm][nn][j];
            }
        }
    }
}

extern "C" void kernel_launch(void* const* d_in, const int* in_sizes, int n_in,
                              void* d_out, int out_size, void* d_ws, size_t ws_size,
                              hipStream_t stream)
{
    const float* x     = (const float*)d_in[0];
    const int*   eidx  = (const int*)  d_in[1];
    const float* ew    = (const float*)d_in[2];
    const float* ea    = (const float*)d_in[3];
    const float* Wmsg  = (const float*)d_in[4];
    const float* Wself = (const float*)d_in[5];
    float*       out   = (float*)d_out;

    int N = in_sizes[0] / DIM;
    int E = in_sizes[1] / 2;
    int Npad = (N + 127) & ~127;
    const int* src = eidx;
    const int* dst = eidx + E;

    // ---- workspace layout ----
    unsigned short* SA = (unsigned short*)d_ws;            // Npad*256 bf16
    unsigned short* Bt = SA + (size_t)Npad * 256;          // 128*512 bf16
    float* deg  = (float*)(Bt + 128 * 512);                // N f
    int* counts = (int*)(deg + N);                         // N
    int* starts = counts + N;                              // N+1
    int* cursor = starts + N + 1;                          // N
    int* bsums  = cursor + N;                              // 256
    int* elist  = bsums + 256;                             // E

    int nb = (N + 1023) / 1024;

    k_zero<<<(N + 255) / 256, 256, 0, stream>>>(counts, N);

    int eblocks = (E + 255) / 256;
    k_hist<<<eblocks, 256, 0, stream>>>(dst, counts, E);
    k_blocksum<<<nb, 256, 0, stream>>>(counts, bsums, N);
    k_scanb<<<1, 256, 0, stream>>>(bsums, nb);
    k_scan<<<nb, 256, 0, stream>>>(counts, bsums, starts, cursor, N, E);
    k_fill<<<eblocks, 256, 0, stream>>>(dst, cursor, elist, E);

    long long rthreads = (long long)N * 64;
    int rblocks = (int)((rthreads + 255) / 256);
    k_node_reduce<<<rblocks, 256, 0, stream>>>(x, src, ew, ea, starts, elist,
                                               SA, deg, N);

    k_wcvt<<<(128 * 512 + 255) / 256, 256, 0, stream>>>(Wmsg, Wself, Bt);

    k_gemm<<<Npad / 128, 256, 0, stream>>>(x, SA, Bt, deg, out, N);
}

// Round 5
// 245.369 us; speedup vs baseline: 5.3757x; 1.0499x over previous
//
#include <hip/hip_runtime.h>

#define DIM 128

typedef __attribute__((ext_vector_type(8))) short short8;
typedef __attribute__((ext_vector_type(4))) float f32x4;

__device__ inline unsigned short f2bf(float f) {
    unsigned int u = __builtin_bit_cast(unsigned int, f);
    unsigned int r = (u + 0x7FFFu + ((u >> 16) & 1u)) >> 16;   // RNE
    return (unsigned short)r;
}
__device__ inline unsigned int packbf2(float a, float b) {
    return (unsigned int)f2bf(a) | ((unsigned int)f2bf(b) << 16);
}

// ---------------------------------------------------------------------------
// Phase 0: zero the counts array
// ---------------------------------------------------------------------------
__global__ __launch_bounds__(256) void k_zero(int* __restrict__ p, int n)
{
    int i = blockIdx.x * blockDim.x + threadIdx.x;
    if (i < n) p[i] = 0;
}

// ---------------------------------------------------------------------------
// Phase 1: histogram of dst -> counts[n]
// ---------------------------------------------------------------------------
__global__ __launch_bounds__(256) void k_hist(const int* __restrict__ dst,
                                              int* __restrict__ counts, int E)
{
    int e = blockIdx.x * blockDim.x + threadIdx.x;
    if (e < E) atomicAdd(&counts[dst[e]], 1);
}

// ---------------------------------------------------------------------------
// Phase 2a: per-block (1024-elem) partial sums of counts
// ---------------------------------------------------------------------------
__global__ __launch_bounds__(256) void k_blocksum(const int* __restrict__ counts,
                                                  int* __restrict__ bsums, int N)
{
    __shared__ int sd[256];
    int b = blockIdx.x, t = threadIdx.x;
    int base = b * 1024 + t * 4;
    int s = 0;
    #pragma unroll
    for (int i = 0; i < 4; ++i) {
        int idx = base + i;
        if (idx < N) s += counts[idx];
    }
    sd[t] = s; __syncthreads();
    for (int off = 128; off > 0; off >>= 1) {
        if (t < off) sd[t] += sd[t + off];
        __syncthreads();
    }
    if (t == 0) bsums[b] = sd[0];
}

// ---------------------------------------------------------------------------
// Phase 2b: exclusive scan of block sums (single block; nb <= 256)
// ---------------------------------------------------------------------------
__global__ __launch_bounds__(256) void k_scanb(int* __restrict__ bsums, int nb)
{
    __shared__ int sd[256];
    int t = threadIdx.x;
    int v = (t < nb) ? bsums[t] : 0;
    sd[t] = v; __syncthreads();
    for (int off = 1; off < 256; off <<= 1) {
        int add = (t >= off) ? sd[t - off] : 0;
        __syncthreads();
        sd[t] += add;
        __syncthreads();
    }
    if (t < nb) bsums[t] = sd[t] - v;   // exclusive
}

// ---------------------------------------------------------------------------
// Phase 2c: per-block exclusive scan of counts + block offset -> starts, cursor
// ---------------------------------------------------------------------------
__global__ __launch_bounds__(256) void k_scan(const int* __restrict__ counts,
                                              const int* __restrict__ bsums,
                                              int* __restrict__ starts,
                                              int* __restrict__ cursor,
                                              int N, int E)
{
    __shared__ int sd[256];
    int b = blockIdx.x, t = threadIdx.x;
    int base = b * 1024 + t * 4;
    int c0 = 0, c1 = 0, c2 = 0, c3 = 0;
    if (base     < N) c0 = counts[base];
    if (base + 1 < N) c1 = counts[base + 1];
    if (base + 2 < N) c2 = counts[base + 2];
    if (base + 3 < N) c3 = counts[base + 3];
    int s = c0 + c1 + c2 + c3;
    sd[t] = s; __syncthreads();
    for (int off = 1; off < 256; off <<= 1) {
        int add = (t >= off) ? sd[t - off] : 0;
        __syncthreads();
        sd[t] += add;
        __syncthreads();
    }
    int run = bsums[b] + sd[t] - s;
    if (base     < N) { starts[base]     = run; cursor[base]     = run; run += c0; }
    if (base + 1 < N) { starts[base + 1] = run; cursor[base + 1] = run; run += c1; }
    if (base + 2 < N) { starts[base + 2] = run; cursor[base + 2] = run; run += c2; }
    if (base + 3 < N) { starts[base + 3] = run; cursor[base + 3] = run; run += c3; }
    if (b == 0 && t == 0) starts[N] = E;
}

// ---------------------------------------------------------------------------
// Phase 3: bucket fill with full edge records:
//   edata[start[dst]+k] = { e, src[e], bits(w[e]), 0 }  (one 16B store)
// src/w reads are coalesced by e; reduce kernel then reads metadata
// contiguously per bucket (no random 4B gathers there).
// ---------------------------------------------------------------------------
__global__ __launch_bounds__(256) void k_fill(const int* __restrict__ dst,
                                              const int* __restrict__ src,
                                              const float* __restrict__ w,
                                              int* __restrict__ cursor,
                                              int4* __restrict__ edata, int E)
{
    int e = blockIdx.x * blockDim.x + threadIdx.x;
    if (e < E) {
        int p = atomicAdd(&cursor[dst[e]], 1);
        int4 md;
        md.x = e;
        md.y = src[e];
        md.z = __float_as_int(w[e]);
        md.w = 0;
        edata[p] = md;
    }
}

// ---------------------------------------------------------------------------
// Phase 4: one wave per node. Metadata loaded lane-parallel (one int4 per
// lane per 64-edge chunk), broadcast via shfl; row loads 4-edge unrolled
// (8 independent 8B loads in flight). deg via wave shuffle-reduce.
// ---------------------------------------------------------------------------
__global__ __launch_bounds__(256) void k_node_reduce(
    const float* __restrict__ x,
    const float* __restrict__ ea,
    const int*   __restrict__ starts,
    const int4*  __restrict__ edata,
    unsigned short* __restrict__ SA,   // [N][256] bf16
    float* __restrict__ deg,           // [N]
    int N)
{
    int wid  = (blockIdx.x * blockDim.x + threadIdx.x) >> 6;
    int lane = threadIdx.x & 63;
    if (wid >= N) return;

    int beg = starts[wid];
    int end = starts[wid + 1];

    float2 sacc = {0.f, 0.f};
    float2 aacc = {0.f, 0.f};
    float  wpart = 0.f;

    int xoff = lane * 2;

    for (int base = beg; base < end; base += 64) {
        int idx = base + lane;
        int me = 0, ms = 0; float mw = 0.f;
        if (idx < end) {
            int4 md = edata[idx];
            me = md.x; ms = md.y; mw = __int_as_float(md.z);
            wpart += mw;
        }
        int cnt = end - base; if (cnt > 64) cnt = 64;

        int j = 0;
        for (; j + 4 <= cnt; j += 4) {
            int   e0 = __shfl(me, j),     e1 = __shfl(me, j + 1);
            int   e2 = __shfl(me, j + 2), e3 = __shfl(me, j + 3);
            int   s0 = __shfl(ms, j),     s1 = __shfl(ms, j + 1);
            int   s2 = __shfl(ms, j + 2), s3 = __shfl(ms, j + 3);
            float w0 = __shfl(mw, j),     w1 = __shfl(mw, j + 1);
            float w2 = __shfl(mw, j + 2), w3 = __shfl(mw, j + 3);

            float2 x0 = *(const float2*)(x  + (size_t)s0 * DIM + xoff);
            float2 x1 = *(const float2*)(x  + (size_t)s1 * DIM + xoff);
            float2 x2 = *(const float2*)(x  + (size_t)s2 * DIM + xoff);
            float2 x3 = *(const float2*)(x  + (size_t)s3 * DIM + xoff);
            float2 v0 = *(const float2*)(ea + (size_t)e0 * DIM + xoff);
            float2 v1 = *(const float2*)(ea + (size_t)e1 * DIM + xoff);
            float2 v2 = *(const float2*)(ea + (size_t)e2 * DIM + xoff);
            float2 v3 = *(const float2*)(ea + (size_t)e3 * DIM + xoff);

            sacc.x += w0 * x0.x + w1 * x1.x + w2 * x2.x + w3 * x3.x;
            sacc.y += w0 * x0.y + w1 * x1.y + w2 * x2.y + w3 * x3.y;
            aacc.x += w0 * v0.x + w1 * v1.x + w2 * v2.x + w3 * v3.x;
            aacc.y += w0 * v0.y + w1 * v1.y + w2 * v2.y + w3 * v3.y;
        }
        for (; j < cnt; ++j) {
            int   e0 = __shfl(me, j);
            int   s0 = __shfl(ms, j);
            float w0 = __shfl(mw, j);
            float2 x0 = *(const float2*)(x  + (size_t)s0 * DIM + xoff);
            float2 v0 = *(const float2*)(ea + (size_t)e0 * DIM + xoff);
            sacc.x += w0 * x0.x; sacc.y += w0 * x0.y;
            aacc.x += w0 * v0.x; aacc.y += w0 * v0.y;
        }
    }

    unsigned short* row = SA + (size_t)wid * 256;
    ushort2 o;
    o.x = f2bf(sacc.x); o.y = f2bf(sacc.y);
    *(ushort2*)(row +       xoff) = o;                 // S -> W_j
    o.x = f2bf(aacc.x); o.y = f2bf(aacc.y);
    *(ushort2*)(row + 128 + xoff) = o;                 // A -> W_e

    // wave-reduce wpart -> deg
    #pragma unroll
    for (int off = 32; off > 0; off >>= 1)
        wpart += __shfl_xor(wpart, off);
    if (lane == 0) deg[wid] = wpart;
}

// ---------------------------------------------------------------------------
// Phase 5a: weights -> bf16, transposed to Bt[n][k].
// k: 0-127 = W_i, 128-255 = W_self, 256-383 = W_j, 384-511 = W_e.
// ---------------------------------------------------------------------------
__global__ __launch_bounds__(256) void k_wcvt(const float* __restrict__ Wmsg,
                                              const float* __restrict__ Wself,
                                              unsigned short* __restrict__ Bt)
{
    int idx = blockIdx.x * blockDim.x + threadIdx.x;
    if (idx >= 128 * 512) return;
    int n = idx >> 9;
    int k = idx & 511;
    float v;
    if (k < 128)      v = Wmsg [(size_t)k * DIM + n];          // W_i
    else if (k < 256) v = Wself[(size_t)(k - 128) * DIM + n];  // W_self
    else              v = Wmsg [(size_t)(k - 128) * DIM + n];  // W_j, W_e
    Bt[(size_t)n * 512 + k] = f2bf(v);
}

// ---------------------------------------------------------------------------
// Phase 5b: MFMA GEMM  out = [deg*x | x | S | A] @ Bt^T. A K-chunks 0-1 =
// deg*x (from fp32 x), 2-3 = x, 4-7 = SA. B frags direct from global (L2).
// ---------------------------------------------------------------------------
__global__ __launch_bounds__(256) void k_gemm(
    const float* __restrict__ x,             // [N][128] fp32
    const unsigned short* __restrict__ SA,   // [N][256] bf16
    const unsigned short* __restrict__ Bt,   // [128][512] bf16
    const float* __restrict__ deg,           // [N]
    float* __restrict__ out, int N)
{
    __shared__ unsigned short As[2][128 * 64];
    __shared__ float dgs[128];

    int t    = threadIdx.x;
    int lane = t & 63;
    int w    = t >> 6;
    int wr   = w >> 1, wc = w & 1;
    int row0 = blockIdx.x * 128;
    int lr   = t >> 3;          // 0..31
    int lc   = (t & 7) * 8;     // bf16 units

    if (t < 128) {
        int g = row0 + t;
        dgs[t] = (g < N) ? deg[g] : 0.f;
    }
    __syncthreads();

    f32x4 acc[4][4];
    #pragma unroll
    for (int m = 0; m < 4; ++m)
        #pragma unroll
        for (int n = 0; n < 4; ++n)
            acc[m][n] = (f32x4){0.f, 0.f, 0.f, 0.f};

    float4 fa[4], fb[4];

    #pragma unroll
    for (int r = 0; r < 4; ++r) {
        int row = r * 32 + lr;
        int g = row0 + row; if (g >= N) g = N - 1;
        const float* xp = x + (size_t)g * DIM + lc;
        fa[r] = *(const float4*)xp;
        fb[r] = *(const float4*)(xp + 4);
    }
    #pragma unroll
    for (int r = 0; r < 4; ++r) {
        int row = r * 32 + lr;
        float d = dgs[row];
        uint4 u;
        u.x = packbf2(d * fa[r].x, d * fa[r].y);
        u.y = packbf2(d * fa[r].z, d * fa[r].w);
        u.z = packbf2(d * fb[r].x, d * fb[r].y);
        u.w = packbf2(d * fb[r].z, d * fb[r].w);
        *(uint4*)&As[0][row * 64 + (lc ^ ((row & 7) << 3))] = u;
    }
    __syncthreads();

    for (int s = 0; s < 8; ++s) {
        int cur = s & 1;
        int sn  = s + 1;

        if (sn < 8) {
            if (sn < 4) {
                int k0 = (sn & 1) * 64;
                #pragma unroll
                for (int r = 0; r < 4; ++r) {
                    int row = r * 32 + lr;
                    int g = row0 + row; if (g >= N) g = N - 1;
                    const float* xp = x + (size_t)g * DIM + k0 + lc;
                    fa[r] = *(const float4*)xp;
                    fb[r] = *(const float4*)(xp + 4);
                }
            } else {
                int k0 = (sn - 4) * 64;
                #pragma unroll
                for (int r = 0; r < 4; ++r) {
                    int row = r * 32 + lr;
                    int g = row0 + row; if (g >= N) g = N - 1;
                    fa[r] = *(const float4*)(SA + (size_t)g * 256 + k0 + lc);
                }
            }
        }

        int bk = s * 64;
        #pragma unroll
        for (int kk = 0; kk < 2; ++kk) {
            int colb = kk * 32 + (lane >> 4) * 8;
            short8 a[4], b[4];
            #pragma unroll
            for (int mm = 0; mm < 4; ++mm) {
                int row = wr * 64 + mm * 16 + (lane & 15);
                a[mm] = *(const short8*)&As[cur][row * 64 + (colb ^ ((row & 7) << 3))];
            }
            int ck = bk + colb;
            #pragma unroll
            for (int nn = 0; nn < 4; ++nn) {
                int n = wc * 64 + nn * 16 + (lane & 15);
                b[nn] = *(const short8*)(Bt + (size_t)n * 512 + ck);
            }
            #pragma unroll
            for (int mm = 0; mm < 4; ++mm)
                #pragma unroll
                for (int nn = 0; nn < 4; ++nn)
                    acc[mm][nn] = __builtin_amdgcn_mfma_f32_16x16x32_bf16(
                        a[mm], b[nn], acc[mm][nn], 0, 0, 0);
        }

        if (sn < 8) {
            int nxt = cur ^ 1;
            #pragma unroll
            for (int r = 0; r < 4; ++r) {
                int row = r * 32 + lr;
                uint4 u;
                if (sn < 2) {
                    float d = dgs[row];
                    u.x = packbf2(d * fa[r].x, d * fa[r].y);
                    u.y = packbf2(d * fa[r].z, d * fa[r].w);
                    u.z = packbf2(d * fb[r].x, d * fb[r].y);
                    u.w = packbf2(d * fb[r].z, d * fb[r].w);
                } else if (sn < 4) {
                    u.x = packbf2(fa[r].x, fa[r].y);
                    u.y = packbf2(fa[r].z, fa[r].w);
                    u.z = packbf2(fb[r].x, fb[r].y);
                    u.w = packbf2(fb[r].z, fb[r].w);
                } else {
                    u = __builtin_bit_cast(uint4, fa[r]);
                }
                *(uint4*)&As[nxt][row * 64 + (lc ^ ((row & 7) << 3))] = u;
            }
            __syncthreads();
        }
    }

    #pragma unroll
    for (int mm = 0; mm < 4; ++mm) {
        #pragma unroll
        for (int j = 0; j < 4; ++j) {
            int m  = wr * 64 + mm * 16 + (lane >> 4) * 4 + j;
            int gm = row0 + m;
            if (gm >= N) continue;
            #pragma unroll
            for (int nn = 0; nn < 4; ++nn) {
                int c = wc * 64 + nn * 16 + (lane & 15);
                out[(size_t)gm * DIM + c] = acc[mm][nn][j];
            }
        }
    }
}

extern "C" void kernel_launch(void* const* d_in, const int* in_sizes, int n_in,
                              void* d_out, int out_size, void* d_ws, size_t ws_size,
                              hipStream_t stream)
{
    const float* x     = (const float*)d_in[0];
    const int*   eidx  = (const int*)  d_in[1];
    const float* ew    = (const float*)d_in[2];
    const float* ea    = (const float*)d_in[3];
    const float* Wmsg  = (const float*)d_in[4];
    const float* Wself = (const float*)d_in[5];
    float*       out   = (float*)d_out;

    int N = in_sizes[0] / DIM;
    int E = in_sizes[1] / 2;
    int Npad = (N + 127) & ~127;
    const int* src = eidx;
    const int* dst = eidx + E;

    // ---- workspace layout (16B-aligned blocks first) ----
    unsigned short* SA = (unsigned short*)d_ws;            // Npad*256 bf16
    unsigned short* Bt = SA + (size_t)Npad * 256;          // 128*512 bf16
    int4* edata = (int4*)(Bt + 128 * 512);                 // E int4
    float* deg  = (float*)(edata + E);                     // N f
    int* counts = (int*)(deg + N);                         // N
    int* starts = counts + N;                              // N+1
    int* cursor = starts + N + 1;                          // N
    int* bsums  = cursor + N;                              // 256

    int nb = (N + 1023) / 1024;

    k_zero<<<(N + 255) / 256, 256, 0, stream>>>(counts, N);

    int eblocks = (E + 255) / 256;
    k_hist<<<eblocks, 256, 0, stream>>>(dst, counts, E);
    k_blocksum<<<nb, 256, 0, stream>>>(counts, bsums, N);
    k_scanb<<<1, 256, 0, stream>>>(bsums, nb);
    k_scan<<<nb, 256, 0, stream>>>(counts, bsums, starts, cursor, N, E);
    k_fill<<<eblocks, 256, 0, stream>>>(dst, src, ew, cursor, edata, E);

    long long rthreads = (long long)N * 64;
    int rblocks = (int)((rthreads + 255) / 256);
    k_node_reduce<<<rblocks, 256, 0, stream>>>(x, ea, starts, edata, SA, deg, N);

    k_wcvt<<<(128 * 512 + 255) / 256, 256, 0, stream>>>(Wmsg, Wself, Bt);

    k_gemm<<<Npad / 128, 256, 0, stream>>>(x, SA, Bt, deg, out, N);
}